// Round 7
// baseline (56.059 us; speedup 1.0000x reference)
//
#include <hip/hip_runtime.h>
#include <math.h>

#define NPTS 8192
#define NSEG 64            // j-segments per slide (128 pts each)
#define NRB 20
#define NAB 72
#define NHB 92             // NRB+NAB
// ws layout (int units):
#define HP_OFF 0           // hist partials: 12 blocks x 92 ints
#define CC_OFF 1152        // collision partial counts: 96 ints
#define DONE_OFF 1260      // done counter for finisher
#define DWS_OFF 2048       // float area: 64 seg-planes x 24576 rows

__device__ __forceinline__ const float* slide_ptr(const float* c0, const float* c1,
                                                  const float* c2, int s) {
  return s == 0 ? c0 : (s == 1 ? c1 : c2);
}

// 780 blocks: 0..11 histogram units (3 slides x 4 parts of 2048 pts),
// 12..779 pair sweep (3 slides x 4 rowblocks(2048) x 64 segs(128 pts)),
// 8 rows/thread, dot-form, partial-min stored (no atomics in sweep path).
__global__ __launch_bounds__(256) void sweep_kernel(const float* __restrict__ c0,
                                                    const float* __restrict__ c1,
                                                    const float* __restrict__ c2,
                                                    int* __restrict__ ws) {
  const int b = blockIdx.x;
  const int t = threadIdx.x;

  if (b < 12) {
    // ---- histogram unit (bit-exact chains, unchanged from R5) ----
    if (b == 0 && t == 0) ws[DONE_OFF] = 0;   // reset finisher counter each call
    const int s = b >> 2, part = b & 3;
    const float4* c4 = (const float4*)slide_ptr(c0, c1, c2, s);

    __shared__ double redd[256];
    __shared__ float  redf[256];
    __shared__ float  cxs, cys, rmaxs;
    __shared__ int    h[NHB];

    double sx = 0.0, sy = 0.0;
    for (int j = 0; j < 16; ++j) {
      float4 v = c4[t + j * 256];
      sx += (double)v.x + (double)v.z;
      sy += (double)v.y + (double)v.w;
    }
    redd[t] = sx; __syncthreads();
    for (int o = 128; o > 0; o >>= 1) { if (t < o) redd[t] += redd[t + o]; __syncthreads(); }
    if (t == 0) cxs = (float)(redd[0] / (double)NPTS);
    __syncthreads();
    redd[t] = sy; __syncthreads();
    for (int o = 128; o > 0; o >>= 1) { if (t < o) redd[t] += redd[t + o]; __syncthreads(); }
    if (t == 0) cys = (float)(redd[0] / (double)NPTS);
    __syncthreads();
    const float cx = cxs, cy = cys;

    float rm = 0.0f;
    for (int j = 0; j < 16; ++j) {
      float4 v = c4[t + j * 256];
      float dx0 = __fsub_rn(v.x, cx), dy0 = __fsub_rn(v.y, cy);
      float dx1 = __fsub_rn(v.z, cx), dy1 = __fsub_rn(v.w, cy);
      float r0 = __fsqrt_rn(__fadd_rn(__fmul_rn(dx0, dx0), __fmul_rn(dy0, dy0)));
      float r1 = __fsqrt_rn(__fadd_rn(__fmul_rn(dx1, dx1), __fmul_rn(dy1, dy1)));
      rm = fmaxf(rm, fmaxf(r0, r1));
    }
    redf[t] = rm; __syncthreads();
    for (int o = 128; o > 0; o >>= 1) { if (t < o) redf[t] = fmaxf(redf[t], redf[t + o]); __syncthreads(); }
    if (t == 0) rmaxs = __fadd_rn(redf[0], 1e-8f);
    for (int i = t; i < NHB; i += 256) h[i] = 0;
    __syncthreads();
    const float rmaxp = rmaxs;

    for (int j = 0; j < 4; ++j) {
      float4 v = c4[part * 1024 + j * 256 + t];
      #pragma unroll
      for (int half = 0; half < 2; ++half) {
        float dx = __fsub_rn(half ? v.z : v.x, cx);
        float dy = __fsub_rn(half ? v.w : v.y, cy);
        float r  = __fsqrt_rn(__fadd_rn(__fmul_rn(dx, dx), __fmul_rn(dy, dy)));
        float rn = __fdiv_rn(r, rmaxp);
        int ri = (int)floorf(__fmul_rn(rn, 20.0f));
        ri = min(max(ri, 0), NRB - 1);
        atomicAdd(&h[ri], 1);
        float ang = (float)atan2((double)dy, (double)dx);
        float tt = __fadd_rn(ang, 3.14159274101257324f);   // + float(pi)
        float uu = __fdiv_rn(tt, 6.28318548202514648f);    // / float(2*pi)
        float vv = __fmul_rn(uu, 72.0f);
        int ai = (int)floorf(vv);
        ai = min(max(ai, 0), NAB - 1);
        atomicAdd(&h[NRB + ai], 1);
      }
    }
    __syncthreads();
    if (t < NHB) ws[HP_OFF + b * NHB + t] = h[t];
    return;
  }

  // ---- pair sweep ----
  const int b2  = b - 12;
  const int s   = b2 >> 8;        // 256 blocks per slide
  const int rem = b2 & 255;
  const int rb  = rem >> 6;       // rowblock: 2048 rows
  const int seg = rem & 63;       // j-segment: 128 pts (64 float4)
  const float2* coords = (const float2*)slide_ptr(c0, c1, c2, s);
  const float4* c4 = (const float4*)coords;

  __shared__ float4 txy[64];
  __shared__ float2 tqq[64];      // |q|^2/2 for the 2 packed points
  if (t < 64) {
    float4 q = c4[seg * 64 + t];
    txy[t] = q;
    tqq[t] = make_float2(0.5f * fmaf(q.y, q.y, q.x * q.x),
                         0.5f * fmaf(q.w, q.w, q.z * q.z));
  }

  const int r0 = rb * 2048;
  float px[8], py[8], pp[8], dm[8];
  #pragma unroll
  for (int k = 0; k < 8; ++k) {
    float2 p = coords[r0 + t + k * 256];
    px[k] = p.x; py[k] = p.y;
    pp[k] = fmaf(p.y, p.y, p.x * p.x);
    dm[k] = INFINITY;             // min over (|q|^2/2 - p.q)
  }
  __syncthreads();

  if ((seg >> 4) == rb) {
    // tile overlaps this rowblock: per-row poison index into the 128-pt tile
    int diag[8];
    #pragma unroll
    for (int k = 0; k < 8; ++k) {
      int d = r0 + t + k * 256 - seg * 128;
      diag[k] = ((unsigned)d < 128u) ? d : -1;
    }
    #pragma unroll 4
    for (int u = 0; u < 64; ++u) {
      float4 q = txy[u];
      float2 qq = tqq[u];
      #pragma unroll
      for (int k = 0; k < 8; ++k) {
        float v0 = fmaf(-py[k], q.y, fmaf(-px[k], q.x, qq.x));
        float v1 = fmaf(-py[k], q.w, fmaf(-px[k], q.z, qq.y));
        v0 = (2 * u == diag[k])     ? INFINITY : v0;
        v1 = (2 * u + 1 == diag[k]) ? INFINITY : v1;
        dm[k] = fminf(dm[k], fminf(v0, v1));
      }
    }
  } else {
    #pragma unroll 8
    for (int u = 0; u < 64; ++u) {
      float4 q = txy[u];
      float2 qq = tqq[u];
      #pragma unroll
      for (int k = 0; k < 8; ++k) {
        float v0 = fmaf(-py[k], q.y, fmaf(-px[k], q.x, qq.x));
        float v1 = fmaf(-py[k], q.w, fmaf(-px[k], q.z, qq.y));
        dm[k] = fminf(dm[k], fminf(v0, v1));   // fuses to v_min3
      }
    }
  }

  float* dws = (float*)(ws + DWS_OFF);
  const int srow = s * NPTS + r0 + t;
  #pragma unroll
  for (int k = 0; k < 8; ++k)
    dws[seg * 24576 + srow + k * 256] = fmaf(2.0f, dm[k], pp[k]);   // partial-min d2
}

// 96 blocks: collision counts (256 rows each); the LAST block to finish also
// runs the descriptor/variance finisher (done-counter, agent-scope atomics).
__global__ __launch_bounds__(256) void finish_kernel(const int* __restrict__ wsc,
                                                     int* __restrict__ ws,
                                                     float* __restrict__ out) {
  const int b = blockIdx.x;
  const int t = threadIdx.x;

  const float* dws = (const float*)(ws + DWS_OFF);
  const int row = b * 256 + t;
  float m = INFINITY;
  #pragma unroll 8
  for (int g = 0; g < NSEG; ++g) m = fminf(m, dws[g * 24576 + row]);
  __shared__ int red[256];
  __shared__ bool lastf;
  red[t] = (m < 1e-4f) ? 1 : 0;    // d<0.01 <=> d2<1e-4
  __syncthreads();
  for (int o = 128; o > 0; o >>= 1) { if (t < o) red[t] += red[t + o]; __syncthreads(); }
  if (t == 0) {
    __hip_atomic_store(&ws[CC_OFF + b], red[0], __ATOMIC_RELEASE, __HIP_MEMORY_SCOPE_AGENT);
    int old = __hip_atomic_fetch_add(&ws[DONE_OFF], 1, __ATOMIC_ACQ_REL, __HIP_MEMORY_SCOPE_AGENT);
    lastf = (old == 95);
  }
  __syncthreads();
  if (!lastf) return;

  // ---- finisher (runs in exactly one block) ----
  __shared__ int ah[3][NHB];
  __shared__ double fr[15][8], fi[15][8];
  __shared__ float descs[3][26];

  for (int i = t; i < 3 * NHB; i += 256) {
    int s = i / NHB, bin = i % NHB;
    int v = 0;
    #pragma unroll
    for (int p = 0; p < 4; ++p) v += wsc[HP_OFF + (s * 4 + p) * NHB + bin];
    ah[s][bin] = v;
  }
  __syncthreads();

  if (t < 120) {
    const int part = t & 7;
    const int sk = t >> 3;        // slide*5 + k
    const int s = sk / 5;
    const int k = sk % 5;
    const float meanv = __fdiv_rn(8192.0f, 72.0f);
    double sr = 0.0, si = 0.0;
    for (int j = part; j < NAB; j += 8) {
      float a = __fsub_rn((float)ah[s][NRB + j], meanv);
      double ang = -2.0 * M_PI * (double)(j * k) / 72.0;
      double sn, cs;
      sincos(ang, &sn, &cs);
      sr += (double)a * cs;
      si += (double)a * sn;
    }
    fr[sk][part] = sr; fi[sk][part] = si;
  }
  if (t >= 120 && t < 123) {
    int s = t - 120;
    int c = 0;
    for (int i = 0; i < 32; ++i)
      c += __hip_atomic_load(&ws[CC_OFF + s * 32 + i], __ATOMIC_ACQUIRE,
                             __HIP_MEMORY_SCOPE_AGENT);
    descs[s][25] = __fdiv_rn((float)c, 8192.0f);
  }
  if (t >= 128 && t < 188) {
    int i = t - 128;
    descs[i / 20][i % 20] = __fdiv_rn((float)ah[i / 20][i % 20], 8192.0f);
  }
  __syncthreads();
  if (t < 15) {
    double sr = 0.0, si = 0.0;
    #pragma unroll
    for (int p = 0; p < 8; ++p) { sr += fr[t][p]; si += fi[t][p]; }
    descs[t / 5][20 + t % 5] = (float)sqrt(sr * sr + si * si);
  }
  __syncthreads();
  if (t == 0) {
    double acc = 0.0;
    for (int j = 0; j < 26; ++j) {
      double a = descs[0][j], bb = descs[1][j], c = descs[2][j];
      double mm = (a + bb + c) / 3.0;
      acc += ((a - mm) * (a - mm) + (bb - mm) * (bb - mm) + (c - mm) * (c - mm)) * 0.5;
    }
    out[0] = (float)(acc / 26.0);
  }
}

extern "C" void kernel_launch(void* const* d_in, const int* in_sizes, int n_in,
                              void* d_out, int out_size, void* d_ws, size_t ws_size,
                              hipStream_t stream) {
  const float* c0 = (const float*)d_in[0];
  const float* c1 = (const float*)d_in[1];
  const float* c2 = (const float*)d_in[2];
  int* ws = (int*)d_ws;
  float* out = (float*)d_out;
  hipLaunchKernelGGL(sweep_kernel,  dim3(780), dim3(256), 0, stream, c0, c1, c2, ws);
  hipLaunchKernelGGL(finish_kernel, dim3(96),  dim3(256), 0, stream, ws, ws, out);
}

// Round 8
// 49.509 us; speedup vs baseline: 1.1323x; 1.1323x over previous
//
#include <hip/hip_runtime.h>
#include <math.h>

#define NPTS 8192
#define NSEG 64            // j-segments per slide (128 pts each)
#define NRB 20
#define NAB 72
#define NHB 92             // NRB+NAB
// ws layout (int units):
#define HP_OFF 0           // hist partials: 12 blocks x 92 ints
#define CC_OFF 1152        // collision partial counts: 96 ints
#define DWS_OFF 2048       // float area: 64 seg-planes x 24576 rows (6.3 MB)

__device__ __forceinline__ const float* slide_ptr(const float* c0, const float* c1,
                                                  const float* c2, int s) {
  return s == 0 ? c0 : (s == 1 ? c1 : c2);
}

// 768 blocks = 3 slides x 4 rowblocks(2048 rows) x 64 segs(128 pts).
// Pure pair sweep: 8 rows/thread, dot-form distance, |q|^2/2 in registers,
// partial-min d2 STORED (no atomics, no init, replay/poison-safe).
__global__ __launch_bounds__(256) void sweep_kernel(const float* __restrict__ c0,
                                                    const float* __restrict__ c1,
                                                    const float* __restrict__ c2,
                                                    int* __restrict__ ws) {
  const int b = blockIdx.x;
  const int t = threadIdx.x;
  const int s   = b >> 8;         // 256 blocks per slide
  const int rem = b & 255;
  const int rb  = rem >> 6;       // rowblock: 2048 rows
  const int seg = rem & 63;       // j-segment: 128 pts (64 float4)
  const float2* coords = (const float2*)slide_ptr(c0, c1, c2, s);
  const float4* c4 = (const float4*)coords;

  __shared__ float4 txy[64];
  if (t < 64) txy[t] = c4[seg * 64 + t];

  const int r0 = rb * 2048;
  float px[8], py[8], pp[8], dm[8];
  #pragma unroll
  for (int k = 0; k < 8; ++k) {
    float2 p = coords[r0 + t + k * 256];
    px[k] = p.x; py[k] = p.y;
    pp[k] = fmaf(p.y, p.y, p.x * p.x);
    dm[k] = INFINITY;             // min over (|q|^2/2 - p.q)
  }
  __syncthreads();

  if ((seg >> 4) == rb) {
    // tile overlaps this rowblock: per-row poison index into the 128-pt tile
    int diag[8];
    #pragma unroll
    for (int k = 0; k < 8; ++k) {
      int d = r0 + t + k * 256 - seg * 128;
      diag[k] = ((unsigned)d < 128u) ? d : -1;
    }
    #pragma unroll 4
    for (int u = 0; u < 64; ++u) {
      float4 q = txy[u];
      float eq0 = 0.5f * fmaf(q.y, q.y, q.x * q.x);
      float eq1 = 0.5f * fmaf(q.w, q.w, q.z * q.z);
      #pragma unroll
      for (int k = 0; k < 8; ++k) {
        float v0 = fmaf(-py[k], q.y, fmaf(-px[k], q.x, eq0));
        float v1 = fmaf(-py[k], q.w, fmaf(-px[k], q.z, eq1));
        v0 = (2 * u == diag[k])     ? INFINITY : v0;
        v1 = (2 * u + 1 == diag[k]) ? INFINITY : v1;
        dm[k] = fminf(dm[k], fminf(v0, v1));
      }
    }
  } else {
    #pragma unroll 8
    for (int u = 0; u < 64; ++u) {
      float4 q = txy[u];
      float eq0 = 0.5f * fmaf(q.y, q.y, q.x * q.x);
      float eq1 = 0.5f * fmaf(q.w, q.w, q.z * q.z);
      #pragma unroll
      for (int k = 0; k < 8; ++k) {
        float v0 = fmaf(-py[k], q.y, fmaf(-px[k], q.x, eq0));
        float v1 = fmaf(-py[k], q.w, fmaf(-px[k], q.z, eq1));
        dm[k] = fminf(dm[k], fminf(v0, v1));   // fuses to v_min3
      }
    }
  }

  float* dws = (float*)(ws + DWS_OFF);
  const int srow = s * NPTS + r0 + t;
  #pragma unroll
  for (int k = 0; k < 8; ++k)
    dws[seg * 24576 + srow + k * 256] = fmaf(2.0f, dm[k], pp[k]);   // partial-min d2
}

// 108 blocks: 0..95 collision-count (256 rows each, reduce 64 seg-planes),
// 96..107 histogram units (3 slides x 4 parts of 2048 pts).
__global__ __launch_bounds__(256) void mid_kernel(const float* __restrict__ c0,
                                                  const float* __restrict__ c1,
                                                  const float* __restrict__ c2,
                                                  int* __restrict__ ws) {
  const int b = blockIdx.x;
  const int t = threadIdx.x;

  if (b < 96) {
    const float* dws = (const float*)(ws + DWS_OFF);
    const int row = b * 256 + t;
    float m = INFINITY;
    #pragma unroll 8
    for (int g = 0; g < NSEG; ++g) m = fminf(m, dws[g * 24576 + row]);
    __shared__ int red[256];
    red[t] = (m < 1e-4f) ? 1 : 0;   // d<0.01 <=> d2<1e-4
    __syncthreads();
    for (int o = 128; o > 0; o >>= 1) { if (t < o) red[t] += red[t + o]; __syncthreads(); }
    if (t == 0) ws[CC_OFF + b] = red[0];
    return;
  }

  // ---- histogram unit (bit-exact chains) ----
  const int hb = b - 96;
  const int s = hb >> 2, part = hb & 3;
  const float4* c4 = (const float4*)slide_ptr(c0, c1, c2, s);

  __shared__ double redd[256];
  __shared__ float  redf[256];
  __shared__ float  cxs, cys, rmaxs;
  __shared__ int    h[NHB];

  // center: full-slide f64 sum (fixed order => deterministic), rounded to f32
  double sx = 0.0, sy = 0.0;
  for (int j = 0; j < 16; ++j) {
    float4 v = c4[t + j * 256];
    sx += (double)v.x + (double)v.z;
    sy += (double)v.y + (double)v.w;
  }
  redd[t] = sx; __syncthreads();
  for (int o = 128; o > 0; o >>= 1) { if (t < o) redd[t] += redd[t + o]; __syncthreads(); }
  if (t == 0) cxs = (float)(redd[0] / (double)NPTS);
  __syncthreads();
  redd[t] = sy; __syncthreads();
  for (int o = 128; o > 0; o >>= 1) { if (t < o) redd[t] += redd[t + o]; __syncthreads(); }
  if (t == 0) cys = (float)(redd[0] / (double)NPTS);
  __syncthreads();
  const float cx = cxs, cy = cys;

  // rmax: full-slide scan (max is order-independent => deterministic)
  float rm = 0.0f;
  for (int j = 0; j < 16; ++j) {
    float4 v = c4[t + j * 256];
    float dx0 = __fsub_rn(v.x, cx), dy0 = __fsub_rn(v.y, cy);
    float dx1 = __fsub_rn(v.z, cx), dy1 = __fsub_rn(v.w, cy);
    float r0 = __fsqrt_rn(__fadd_rn(__fmul_rn(dx0, dx0), __fmul_rn(dy0, dy0)));
    float r1 = __fsqrt_rn(__fadd_rn(__fmul_rn(dx1, dx1), __fmul_rn(dy1, dy1)));
    rm = fmaxf(rm, fmaxf(r0, r1));
  }
  redf[t] = rm; __syncthreads();
  for (int o = 128; o > 0; o >>= 1) { if (t < o) redf[t] = fmaxf(redf[t], redf[t + o]); __syncthreads(); }
  if (t == 0) rmaxs = __fadd_rn(redf[0], 1e-8f);
  for (int i = t; i < NHB; i += 256) h[i] = 0;
  __syncthreads();
  const float rmaxp = rmaxs;

  // bin this block's 2048 points = 1024 float4 (exact f32 chains of the reference)
  for (int j = 0; j < 4; ++j) {
    float4 v = c4[part * 1024 + j * 256 + t];
    #pragma unroll
    for (int half = 0; half < 2; ++half) {
      float dx = __fsub_rn(half ? v.z : v.x, cx);
      float dy = __fsub_rn(half ? v.w : v.y, cy);
      float r  = __fsqrt_rn(__fadd_rn(__fmul_rn(dx, dx), __fmul_rn(dy, dy)));
      float rn = __fdiv_rn(r, rmaxp);
      int ri = (int)floorf(__fmul_rn(rn, 20.0f));
      ri = min(max(ri, 0), NRB - 1);
      atomicAdd(&h[ri], 1);
      float ang = (float)atan2((double)dy, (double)dx);  // correctly-rounded f32 atan2
      float tt = __fadd_rn(ang, 3.14159274101257324f);   // + float(pi)
      float uu = __fdiv_rn(tt, 6.28318548202514648f);    // / float(2*pi)
      float vv = __fmul_rn(uu, 72.0f);
      int ai = (int)floorf(vv);
      ai = min(max(ai, 0), NAB - 1);
      atomicAdd(&h[NRB + ai], 1);
    }
  }
  __syncthreads();
  if (t < NHB) ws[HP_OFF + hb * NHB + t] = h[t];   // partial hist, distinct slot
}

// One block: sum hist partials, DFT magnitudes, collision sums, variance.
__global__ __launch_bounds__(256) void final_kernel(const int* __restrict__ ws,
                                                    float* __restrict__ out) {
  __shared__ int ah[3][NHB];
  __shared__ double fr[15][8], fi[15][8];
  __shared__ float descs[3][26];
  const int t = threadIdx.x;

  for (int i = t; i < 3 * NHB; i += 256) {
    int s = i / NHB, bin = i % NHB;
    int v = 0;
    #pragma unroll
    for (int p = 0; p < 4; ++p) v += ws[HP_OFF + (s * 4 + p) * NHB + bin];
    ah[s][bin] = v;
  }
  __syncthreads();

  if (t < 120) {
    const int part = t & 7;
    const int sk = t >> 3;        // slide*5 + k
    const int s = sk / 5;
    const int k = sk % 5;
    const float meanv = __fdiv_rn(8192.0f, 72.0f);
    double sr = 0.0, si = 0.0;
    for (int j = part; j < NAB; j += 8) {
      float a = __fsub_rn((float)ah[s][NRB + j], meanv);
      double ang = -2.0 * M_PI * (double)(j * k) / 72.0;
      double sn, cs;
      sincos(ang, &sn, &cs);
      sr += (double)a * cs;
      si += (double)a * sn;
    }
    fr[sk][part] = sr; fi[sk][part] = si;
  }
  if (t >= 120 && t < 123) {
    int s = t - 120;
    int c = 0;
    for (int i = 0; i < 32; ++i) c += ws[CC_OFF + s * 32 + i];
    descs[s][25] = __fdiv_rn((float)c, 8192.0f);
  }
  if (t >= 128 && t < 188) {
    int i = t - 128;
    descs[i / 20][i % 20] = __fdiv_rn((float)ah[i / 20][i % 20], 8192.0f);
  }
  __syncthreads();
  if (t < 15) {
    double sr = 0.0, si = 0.0;
    #pragma unroll
    for (int p = 0; p < 8; ++p) { sr += fr[t][p]; si += fi[t][p]; }
    descs[t / 5][20 + t % 5] = (float)sqrt(sr * sr + si * si);
  }
  __syncthreads();
  if (t == 0) {
    double acc = 0.0;
    for (int j = 0; j < 26; ++j) {
      double a = descs[0][j], b = descs[1][j], c = descs[2][j];
      double m = (a + b + c) / 3.0;
      acc += ((a - m) * (a - m) + (b - m) * (b - m) + (c - m) * (c - m)) * 0.5;
    }
    out[0] = (float)(acc / 26.0);
  }
}

extern "C" void kernel_launch(void* const* d_in, const int* in_sizes, int n_in,
                              void* d_out, int out_size, void* d_ws, size_t ws_size,
                              hipStream_t stream) {
  const float* c0 = (const float*)d_in[0];
  const float* c1 = (const float*)d_in[1];
  const float* c2 = (const float*)d_in[2];
  int* ws = (int*)d_ws;
  float* out = (float*)d_out;
  hipLaunchKernelGGL(sweep_kernel, dim3(768), dim3(256), 0, stream, c0, c1, c2, ws);
  hipLaunchKernelGGL(mid_kernel,   dim3(108), dim3(256), 0, stream, c0, c1, c2, ws);
  hipLaunchKernelGGL(final_kernel, dim3(1),   dim3(256), 0, stream, ws, out);
}

// Round 9
// 37.157 us; speedup vs baseline: 1.5087x; 1.3324x over previous
//
#include <hip/hip_runtime.h>
#include <math.h>

#define NPTS 8192
#define NRB 20
#define NAB 72
#define NHB 92             // NRB+NAB
// ws layout:
#define HP_OFF 0           // int units: hist partials, 12 blocks x 92 ints
#define CC_OFF 1152        // int units: collision partial counts, 96 ints
#define CNT_BYTE (1u<<20)  // byte offset: grid counts, 3 x 1M int32 (12 MB, memset to 0)
#define SLOT_BYTE (16u<<20)// byte offset: grid slots, 3 x 1M x 4 int32 (48 MB, unzeroed)

__device__ __forceinline__ const float* slide_ptr(const float* c0, const float* c1,
                                                  const float* c2, int s) {
  return s == 0 ? c0 : (s == 1 ? c1 : c2);
}

__device__ __forceinline__ int cell_coord(float v) {
  int g = (int)floorf((v + 5.12f) * 100.0f);
  return min(max(g, 0), 1023);
}

// 108 blocks: 0..95 grid build (one point/thread), 96..107 histogram units
// (3 slides x 4 parts of 2048 pts) — hist code verbatim from verified rounds.
__global__ __launch_bounds__(256) void build_kernel(const float* __restrict__ c0,
                                                    const float* __restrict__ c1,
                                                    const float* __restrict__ c2,
                                                    int* __restrict__ ws) {
  const int b = blockIdx.x;
  const int t = threadIdx.x;

  if (b < 96) {
    int* cnt   = (int*)((char*)ws + CNT_BYTE);
    int* slots = (int*)((char*)ws + SLOT_BYTE);
    const int i  = b * 256 + t;     // 0..24575
    const int s  = i >> 13;         // slide
    const int li = i & 8191;        // point index within slide
    const float2* coords = (const float2*)slide_ptr(c0, c1, c2, s);
    float2 p = coords[li];
    int gx = cell_coord(p.x), gy = cell_coord(p.y);
    int cell = (s << 20) | (gy << 10) | gx;
    int pos = atomicAdd(&cnt[cell], 1);
    if (pos < 4) slots[cell * 4 + pos] = li;
    return;
  }

  // ---- histogram unit (bit-exact chains, verbatim) ----
  const int hb = b - 96;
  const int s = hb >> 2, part = hb & 3;
  const float4* c4 = (const float4*)slide_ptr(c0, c1, c2, s);

  __shared__ double redd[256];
  __shared__ float  redf[256];
  __shared__ float  cxs, cys, rmaxs;
  __shared__ int    h[NHB];

  double sx = 0.0, sy = 0.0;
  for (int j = 0; j < 16; ++j) {
    float4 v = c4[t + j * 256];
    sx += (double)v.x + (double)v.z;
    sy += (double)v.y + (double)v.w;
  }
  redd[t] = sx; __syncthreads();
  for (int o = 128; o > 0; o >>= 1) { if (t < o) redd[t] += redd[t + o]; __syncthreads(); }
  if (t == 0) cxs = (float)(redd[0] / (double)NPTS);
  __syncthreads();
  redd[t] = sy; __syncthreads();
  for (int o = 128; o > 0; o >>= 1) { if (t < o) redd[t] += redd[t + o]; __syncthreads(); }
  if (t == 0) cys = (float)(redd[0] / (double)NPTS);
  __syncthreads();
  const float cx = cxs, cy = cys;

  float rm = 0.0f;
  for (int j = 0; j < 16; ++j) {
    float4 v = c4[t + j * 256];
    float dx0 = __fsub_rn(v.x, cx), dy0 = __fsub_rn(v.y, cy);
    float dx1 = __fsub_rn(v.z, cx), dy1 = __fsub_rn(v.w, cy);
    float r0 = __fsqrt_rn(__fadd_rn(__fmul_rn(dx0, dx0), __fmul_rn(dy0, dy0)));
    float r1 = __fsqrt_rn(__fadd_rn(__fmul_rn(dx1, dx1), __fmul_rn(dy1, dy1)));
    rm = fmaxf(rm, fmaxf(r0, r1));
  }
  redf[t] = rm; __syncthreads();
  for (int o = 128; o > 0; o >>= 1) { if (t < o) redf[t] = fmaxf(redf[t], redf[t + o]); __syncthreads(); }
  if (t == 0) rmaxs = __fadd_rn(redf[0], 1e-8f);
  for (int i = t; i < NHB; i += 256) h[i] = 0;
  __syncthreads();
  const float rmaxp = rmaxs;

  for (int j = 0; j < 4; ++j) {
    float4 v = c4[part * 1024 + j * 256 + t];
    #pragma unroll
    for (int half = 0; half < 2; ++half) {
      float dx = __fsub_rn(half ? v.z : v.x, cx);
      float dy = __fsub_rn(half ? v.w : v.y, cy);
      float r  = __fsqrt_rn(__fadd_rn(__fmul_rn(dx, dx), __fmul_rn(dy, dy)));
      float rn = __fdiv_rn(r, rmaxp);
      int ri = (int)floorf(__fmul_rn(rn, 20.0f));
      ri = min(max(ri, 0), NRB - 1);
      atomicAdd(&h[ri], 1);
      float ang = (float)atan2((double)dy, (double)dx);  // correctly-rounded f32 atan2
      float tt = __fadd_rn(ang, 3.14159274101257324f);   // + float(pi)
      float uu = __fdiv_rn(tt, 6.28318548202514648f);    // / float(2*pi)
      float vv = __fmul_rn(uu, 72.0f);
      int ai = (int)floorf(vv);
      ai = min(max(ai, 0), NAB - 1);
      atomicAdd(&h[NRB + ai], 1);
    }
  }
  __syncthreads();
  if (t < NHB) ws[HP_OFF + hb * NHB + t] = h[t];
}

// 96 blocks x 256: one point/thread, 3x3 neighborhood probe, ballot+popcount.
__global__ __launch_bounds__(256) void probe_kernel(const float* __restrict__ c0,
                                                    const float* __restrict__ c1,
                                                    const float* __restrict__ c2,
                                                    int* __restrict__ ws) {
  const int b = blockIdx.x;
  const int t = threadIdx.x;
  const int* cnt   = (const int*)((const char*)ws + CNT_BYTE);
  const int* slots = (const int*)((const char*)ws + SLOT_BYTE);
  const int i  = b * 256 + t;
  const int s  = i >> 13;
  const int li = i & 8191;
  const float2* coords = (const float2*)slide_ptr(c0, c1, c2, s);
  float2 p = coords[li];
  int gx = cell_coord(p.x), gy = cell_coord(p.y);

  bool hit = false;
  #pragma unroll
  for (int dyc = -1; dyc <= 1; ++dyc) {
    int yy = gy + dyc;
    if ((unsigned)yy > 1023u) continue;
    #pragma unroll
    for (int dxc = -1; dxc <= 1; ++dxc) {
      int xx = gx + dxc;
      if ((unsigned)xx > 1023u) continue;
      int cell = (s << 20) | (yy << 10) | xx;
      int c = min(cnt[cell], 4);
      for (int k = 0; k < c; ++k) {
        int j = slots[cell * 4 + k];
        if (j != li) {
          float2 q = coords[j];
          float dx = p.x - q.x, dy = p.y - q.y;
          hit = hit || (fmaf(dx, dx, dy * dy) < 1e-4f);   // d<0.01 <=> d2<1e-4
        }
      }
    }
  }

  __shared__ int redp[4];
  unsigned long long bal = __ballot(hit);
  if ((t & 63) == 0) redp[t >> 6] = (int)__popcll(bal);
  __syncthreads();
  if (t == 0) ws[CC_OFF + b] = redp[0] + redp[1] + redp[2] + redp[3];
}

// One block: sum hist partials, DFT magnitudes, collision sums, variance.
__global__ __launch_bounds__(256) void final_kernel(const int* __restrict__ ws,
                                                    float* __restrict__ out) {
  __shared__ int ah[3][NHB];
  __shared__ double fr[15][8], fi[15][8];
  __shared__ float descs[3][26];
  const int t = threadIdx.x;

  for (int i = t; i < 3 * NHB; i += 256) {
    int s = i / NHB, bin = i % NHB;
    int v = 0;
    #pragma unroll
    for (int p = 0; p < 4; ++p) v += ws[HP_OFF + (s * 4 + p) * NHB + bin];
    ah[s][bin] = v;
  }
  __syncthreads();

  if (t < 120) {
    const int part = t & 7;
    const int sk = t >> 3;        // slide*5 + k
    const int s = sk / 5;
    const int k = sk % 5;
    const float meanv = __fdiv_rn(8192.0f, 72.0f);
    double sr = 0.0, si = 0.0;
    for (int j = part; j < NAB; j += 8) {
      float a = __fsub_rn((float)ah[s][NRB + j], meanv);
      double ang = -2.0 * M_PI * (double)(j * k) / 72.0;
      double sn, cs;
      sincos(ang, &sn, &cs);
      sr += (double)a * cs;
      si += (double)a * sn;
    }
    fr[sk][part] = sr; fi[sk][part] = si;
  }
  if (t >= 120 && t < 123) {
    int s = t - 120;
    int c = 0;
    for (int i = 0; i < 32; ++i) c += ws[CC_OFF + s * 32 + i];
    descs[s][25] = __fdiv_rn((float)c, 8192.0f);
  }
  if (t >= 128 && t < 188) {
    int i = t - 128;
    descs[i / 20][i % 20] = __fdiv_rn((float)ah[i / 20][i % 20], 8192.0f);
  }
  __syncthreads();
  if (t < 15) {
    double sr = 0.0, si = 0.0;
    #pragma unroll
    for (int p = 0; p < 8; ++p) { sr += fr[t][p]; si += fi[t][p]; }
    descs[t / 5][20 + t % 5] = (float)sqrt(sr * sr + si * si);
  }
  __syncthreads();
  if (t == 0) {
    double acc = 0.0;
    for (int j = 0; j < 26; ++j) {
      double a = descs[0][j], b = descs[1][j], c = descs[2][j];
      double m = (a + b + c) / 3.0;
      acc += ((a - m) * (a - m) + (b - m) * (b - m) + (c - m) * (c - m)) * 0.5;
    }
    out[0] = (float)(acc / 26.0);
  }
}

extern "C" void kernel_launch(void* const* d_in, const int* in_sizes, int n_in,
                              void* d_out, int out_size, void* d_ws, size_t ws_size,
                              hipStream_t stream) {
  const float* c0 = (const float*)d_in[0];
  const float* c1 = (const float*)d_in[1];
  const float* c2 = (const float*)d_in[2];
  int* ws = (int*)d_ws;
  float* out = (float*)d_out;
  // zero the grid counts (3 x 1M int32 = 12 MB); capturable as a graph memset node
  hipMemsetAsync((char*)d_ws + CNT_BYTE, 0, 3u * (1u << 20) * 4u, stream);
  hipLaunchKernelGGL(build_kernel, dim3(108), dim3(256), 0, stream, c0, c1, c2, ws);
  hipLaunchKernelGGL(probe_kernel, dim3(96),  dim3(256), 0, stream, c0, c1, c2, ws);
  hipLaunchKernelGGL(final_kernel, dim3(1),   dim3(256), 0, stream, ws, out);
}